// Round 5
// baseline (121.403 us; speedup 1.0000x reference)
//
#include <hip/hip_runtime.h>
#include <math.h>

// Problem constants
constexpr int Bb = 8;     // batch
constexpr int Ns = 1024;  // tokens (32x32)
constexpr int Es = 256;   // embed
constexpr int NH = 8;     // heads
constexpr int DH = 32;    // head dim
constexpr int Mrows = Bb * Ns;        // 8192
constexpr int NX = Mrows * Es;        // 2097152
constexpr int NQ = 3 * Es * Es;       // 196608
constexpr int NP = Es * Es;           // 65536

typedef __bf16 bf16x8 __attribute__((ext_vector_type(8)));
typedef float  f32x4  __attribute__((ext_vector_type(4)));
union U4B8 { uint4 u; bf16x8 b; unsigned short s[8]; };

__device__ __forceinline__ unsigned short f2bf(float f) {
    union { float f; unsigned u; } c; c.f = f;
    unsigned r = (c.u + 0x7FFFu + ((c.u >> 16) & 1u)) >> 16;
    return (unsigned short)r;
}
__device__ __forceinline__ float bf2f(unsigned short h) {
    union { unsigned u; float f; } c; c.u = ((unsigned)h) << 16;
    return c.f;
}

#define PST 232   // attn P row stride (bf16)

// ---------------------------------------------------------------------------
// R2-R4 post-mortems: (a) persistent+grid-barrier = 60-110us/barrier, dead.
// (b) phases are latency-bound (MfmaUtil<1%, VALU<3%, HBM<3%) and MORE WAVES
// DID NOT HELP (R4 neutral) -> the latency is a serial chain per block: the
// LDS-staged GEMM's 8 barriers + 4 exposed global-load waits per tile, plus
// 1.28M LDS bank conflicts (GLD=72 stride). Fix: K=256 is tiny and operands
// are L2-resident -> load MFMA fragments DIRECTLY from global (same pattern
// attn already uses for K-fragments). Zero barriers, zero LDS, 32 independent
// 16B loads fully unrolled -> one latency exposure, deep MLP.
// ---------------------------------------------------------------------------

// Kernel 0: cast x, qkv_w, proj_w fp32 -> bf16 once. 8 elems/thread.
__global__ __launch_bounds__(256, 8)
void cast_all(const float* __restrict__ x, const float* __restrict__ wq,
              const float* __restrict__ wp, unsigned short* __restrict__ xb,
              unsigned short* __restrict__ wqb, unsigned short* __restrict__ wpb)
{
    int i = (blockIdx.x * 256 + threadIdx.x) * 8;
    const float* src; unsigned short* dst;
    if (i < NX)            { src = x  + i;             dst = xb  + i; }
    else if (i < NX + NQ)  { src = wq + (i - NX);      dst = wqb + (i - NX); }
    else                   { src = wp + (i - NX - NQ); dst = wpb + (i - NX - NQ); }
    float4 f0 = *(const float4*)src;
    float4 f1 = *(const float4*)(src + 4);
    U4B8 u;
    u.s[0] = f2bf(f0.x); u.s[1] = f2bf(f0.y); u.s[2] = f2bf(f0.z); u.s[3] = f2bf(f0.w);
    u.s[4] = f2bf(f1.x); u.s[5] = f2bf(f1.y); u.s[6] = f2bf(f1.z); u.s[7] = f2bf(f1.w);
    *(uint4*)dst = u.u;
}

// ---------------------------------------------------------------------------
// Kernel 1: QKV GEMM, direct-from-global fragments (no LDS, no barriers).
// 64x64 tile, 4 waves (2m x 2n), K=256 fully unrolled: 32 loads + 32 MFMA.
// ---------------------------------------------------------------------------
__global__ __launch_bounds__(256, 4)
void qkv_gemm(const unsigned short* __restrict__ A, const unsigned short* __restrict__ W,
              const float* __restrict__ qkv_b,
              unsigned short* __restrict__ qo, unsigned short* __restrict__ ko,
              unsigned short* __restrict__ vto)
{
    const int t = threadIdx.x;
    const int m0 = (blockIdx.x & 127) * 64;
    const int j0 = (blockIdx.x >> 7) * 64;

    const int lane = t & 63;
    const int wave = t >> 6;
    const int wm = (wave & 1) * 32;
    const int wn = (wave >> 1) * 32;
    const int fm = lane & 15;
    const int fq = lane >> 4;

    // Fragment rows: A rows (m0+wm+fm, +16), W rows (j0+wn+fm, +16); k = ks + fq*8
    const unsigned short* Ar0 = A + (size_t)(m0 + wm + fm) * Es + fq * 8;
    const unsigned short* Ar1 = Ar0 + 16 * Es;
    const unsigned short* Wr0 = W + (size_t)(j0 + wn + fm) * Es + fq * 8;
    const unsigned short* Wr1 = Wr0 + 16 * Es;

    f32x4 acc[2][2];
    #pragma unroll
    for (int i = 0; i < 2; i++)
        #pragma unroll
        for (int j = 0; j < 2; j++)
            acc[i][j] = (f32x4){0.f, 0.f, 0.f, 0.f};

    #pragma unroll
    for (int ks = 0; ks < Es; ks += 32) {
        U4B8 af0, af1, bf0, bf1;
        af0.u = *(const uint4*)(Ar0 + ks);
        af1.u = *(const uint4*)(Ar1 + ks);
        bf0.u = *(const uint4*)(Wr0 + ks);
        bf1.u = *(const uint4*)(Wr1 + ks);
        acc[0][0] = __builtin_amdgcn_mfma_f32_16x16x32_bf16(af0.b, bf0.b, acc[0][0], 0, 0, 0);
        acc[0][1] = __builtin_amdgcn_mfma_f32_16x16x32_bf16(af0.b, bf1.b, acc[0][1], 0, 0, 0);
        acc[1][0] = __builtin_amdgcn_mfma_f32_16x16x32_bf16(af1.b, bf0.b, acc[1][0], 0, 0, 0);
        acc[1][1] = __builtin_amdgcn_mfma_f32_16x16x32_bf16(af1.b, bf1.b, acc[1][1], 0, 0, 0);
    }

    // C/D: col = lane&15, row = quad*4 + reg  (epilogue unchanged, R8-verified)
    #pragma unroll
    for (int mt = 0; mt < 2; mt++) {
        #pragma unroll
        for (int nt = 0; nt < 2; nt++) {
            #pragma unroll
            for (int r = 0; r < 4; r++) {
                int row = m0 + wm + mt * 16 + fq * 4 + r;
                int col = j0 + wn + nt * 16 + fm;
                float val = acc[mt][nt][r] + qkv_b[col];
                int part = col >> 8;           // 0:q 1:k 2:v
                int head = (col >> 5) & 7;
                int d = col & 31;
                int b = row >> 10;
                int n = row & 1023;
                int bh = b * NH + head;
                if (part == 0)
                    qo[((size_t)bh * Ns + n) * DH + d] = f2bf(val * 0.0625f);
                else if (part == 1)
                    ko[((size_t)bh * Ns + n) * DH + d] = f2bf(val);
                else
                    vto[((size_t)bh * DH + d) * Ns + n] = f2bf(val);
            }
        }
    }
}

// ---------------------------------------------------------------------------
// Kernel 2: MFMA attention (unchanged — R4-verified at (256,6)).
// ---------------------------------------------------------------------------
__global__ __launch_bounds__(256, 6)
void attn_mfma2(const unsigned short* __restrict__ qb, const unsigned short* __restrict__ kb,
                const unsigned short* __restrict__ vtb, unsigned short* __restrict__ aob)
{
    __shared__ unsigned short Pb[32 * PST];   // 14848 B
    __shared__ float psum[2][32];

    const int blk = blockIdx.x;          // 0..2047
    const int b   = blk & 7;             // XCD-locality: batch pinned to XCD
    const int u   = blk >> 3;
    const int h   = u & 7;
    const int hq  = u >> 3;
    const int bh  = b * NH + h;

    const int t   = threadIdx.x;
    const int lane = t & 63;
    const int w    = t >> 6;
    const int fm = lane & 15;
    const int fq = lane >> 4;

    int n0c = (hq - 3) * 32;
    n0c = n0c < 0 ? 0 : (n0c > Ns - 224 ? Ns - 224 : n0c);

    const int qbase = (w & 1) * 16;      // query 16-tile
    const int sel   = w >> 1;            // key-tile parity
    const int dbase = (w >> 1) * 16;     // PV dim-tile

    // V^T fragment prefetch (B-operand: n=dim, k=key)
    const unsigned short* vrow = vtb + ((size_t)bh * DH + dbase + fm) * Ns;
    uint4 vpre[7];
    #pragma unroll
    for (int i = 0; i < 7; i++)
        vpre[i] = *(const uint4*)(vrow + n0c + i * 32 + fq * 8);

    // Q fragment (A-operand)
    U4B8 qa;
    qa.u = *(const uint4*)(qb + ((size_t)bh * Ns + hq * 32 + qbase + fm) * DH + fq * 8);

    // S = Q.K^T in C-layout registers (key = kt*16+fm, query = qbase+fq*4+r)
    f32x4 sv[7];
    #pragma unroll
    for (int i = 0; i < 7; i++) {
        int kt = sel + 2 * i;
        U4B8 kf;
        kf.u = *(const uint4*)(kb + ((size_t)bh * Ns + n0c + kt * 16 + fm) * DH + fq * 8);
        sv[i] = __builtin_amdgcn_mfma_f32_16x16x32_bf16(qa.b, kf.b, (f32x4){0.f,0.f,0.f,0.f}, 0, 0, 0);
    }

    // mask + exp (no max shift) + P write + local sum of rounded values
    float sm[4] = {0.f, 0.f, 0.f, 0.f};
    #pragma unroll
    for (int i = 0; i < 7; i++) {
        int kt = sel + 2 * i;
        int g = n0c + kt * 16 + fm;          // absolute key token
        int gh = g >> 5, gw = g & 31;
        int dhh = gh - hq;
        bool okh = (dhh >= -3) && (dhh <= 3);
        #pragma unroll
        for (int r = 0; r < 4; r++) {
            int qc = qbase + fq * 4 + r;
            int dww = gw - qc;
            bool ok = okh && (dww >= -5) && (dww <= 5);
            float p = ok ? __expf(sv[i][r]) : 0.f;
            unsigned short pu = f2bf(p);
            Pb[qc * PST + kt * 16 + fm] = pu;
            sm[r] += bf2f(pu);
        }
    }
    #pragma unroll
    for (int r = 0; r < 4; r++)
        #pragma unroll
        for (int m = 1; m < 16; m <<= 1)
            sm[r] += __shfl_xor(sm[r], m);
    if (fm == 0) {
        #pragma unroll
        for (int r = 0; r < 4; r++)
            psum[sel][qbase + fq * 4 + r] = sm[r];
    }
    __syncthreads();   // P complete + psum visible (single barrier)

    // O = P.V
    f32x4 acc = (f32x4){0.f, 0.f, 0.f, 0.f};
    #pragma unroll
    for (int i = 0; i < 7; i++) {
        U4B8 pa, vb;
        pa.u = *(const uint4*)&Pb[(qbase + fm) * PST + i * 32 + fq * 8];
        vb.u = vpre[i];
        acc = __builtin_amdgcn_mfma_f32_16x16x32_bf16(pa.b, vb.b, acc, 0, 0, 0);
    }

    #pragma unroll
    for (int r = 0; r < 4; r++) {
        int qq = qbase + fq * 4 + r;
        float inv = 1.f / (psum[0][qq] + psum[1][qq]);
        aob[((size_t)(b * Ns) + hq * 32 + qq) * Es + h * DH + dbase + fm] = f2bf(acc[r] * inv);
    }
}

// ---------------------------------------------------------------------------
// Kernel 3: proj GEMM, direct-from-global fragments (no LDS, no barriers).
// ---------------------------------------------------------------------------
__global__ __launch_bounds__(256, 4)
void proj_gemm(const unsigned short* __restrict__ A, const unsigned short* __restrict__ Wb,
               const float* __restrict__ bias, float* __restrict__ out)
{
    const int t = threadIdx.x;
    const int m0 = (blockIdx.x & 127) * 64;
    const int j0 = (blockIdx.x >> 7) * 64;

    const int lane = t & 63;
    const int wave = t >> 6;
    const int wm = (wave & 1) * 32;
    const int wn = (wave >> 1) * 32;
    const int fm = lane & 15;
    const int fq = lane >> 4;

    const unsigned short* Ar0 = A  + (size_t)(m0 + wm + fm) * Es + fq * 8;
    const unsigned short* Ar1 = Ar0 + 16 * Es;
    const unsigned short* Wr0 = Wb + (size_t)(j0 + wn + fm) * Es + fq * 8;
    const unsigned short* Wr1 = Wr0 + 16 * Es;

    f32x4 acc[2][2];
    #pragma unroll
    for (int i = 0; i < 2; i++)
        #pragma unroll
        for (int j = 0; j < 2; j++)
            acc[i][j] = (f32x4){0.f, 0.f, 0.f, 0.f};

    #pragma unroll
    for (int ks = 0; ks < Es; ks += 32) {
        U4B8 af0, af1, bf0, bf1;
        af0.u = *(const uint4*)(Ar0 + ks);
        af1.u = *(const uint4*)(Ar1 + ks);
        bf0.u = *(const uint4*)(Wr0 + ks);
        bf1.u = *(const uint4*)(Wr1 + ks);
        acc[0][0] = __builtin_amdgcn_mfma_f32_16x16x32_bf16(af0.b, bf0.b, acc[0][0], 0, 0, 0);
        acc[0][1] = __builtin_amdgcn_mfma_f32_16x16x32_bf16(af0.b, bf1.b, acc[0][1], 0, 0, 0);
        acc[1][0] = __builtin_amdgcn_mfma_f32_16x16x32_bf16(af1.b, bf0.b, acc[1][0], 0, 0, 0);
        acc[1][1] = __builtin_amdgcn_mfma_f32_16x16x32_bf16(af1.b, bf1.b, acc[1][1], 0, 0, 0);
    }

    #pragma unroll
    for (int mt = 0; mt < 2; mt++) {
        #pragma unroll
        for (int nt = 0; nt < 2; nt++) {
            #pragma unroll
            for (int r = 0; r < 4; r++) {
                int row = m0 + wm + mt * 16 + fq * 4 + r;
                int col = j0 + wn + nt * 16 + fm;
                out[(size_t)row * Es + col] = acc[mt][nt][r] + bias[col];
            }
        }
    }
}

extern "C" void kernel_launch(void* const* d_in, const int* in_sizes, int n_in,
                              void* d_out, int out_size, void* d_ws, size_t ws_size,
                              hipStream_t stream) {
    const float* x      = (const float*)d_in[0];  // [B,N,E]
    const float* qkv_w  = (const float*)d_in[1];  // [3E,E]
    const float* qkv_b  = (const float*)d_in[2];  // [3E]
    const float* proj_w = (const float*)d_in[3];  // [E,E]
    const float* proj_b = (const float*)d_in[4];  // [E]
    float* out = (float*)d_out;                   // [B,N,E]

    unsigned short* xb  = (unsigned short*)d_ws;  // NX bf16
    unsigned short* wqb = xb + NX;                // NQ bf16
    unsigned short* pwb = wqb + NQ;               // NP bf16
    unsigned short* qb  = pwb + NP;               // NX bf16 (q, scaled)
    unsigned short* kb  = qb + NX;                // NX bf16
    unsigned short* vtb = kb + NX;                // NX bf16 (transposed)
    unsigned short* aob = vtb + NX;               // NX bf16 (attn out)

    cast_all<<<dim3((NX + NQ + NP) / 8 / 256), dim3(256), 0, stream>>>(
        x, qkv_w, proj_w, xb, wqb, pwb);

    qkv_gemm<<<dim3(1536), dim3(256), 0, stream>>>(xb, wqb, qkv_b, qb, kb, vtb);

    attn_mfma2<<<dim3(Bb * NH * 32), dim3(256), 0, stream>>>(qb, kb, vtb, aob);

    proj_gemm<<<dim3(128 * 4), dim3(256), 0, stream>>>(aob, pwb, proj_b, out);
}

// Round 6
// 103.656 us; speedup vs baseline: 1.1712x; 1.1712x over previous
//
#include <hip/hip_runtime.h>
#include <math.h>

// Problem constants
constexpr int Bb = 8;     // batch
constexpr int Ns = 1024;  // tokens (32x32)
constexpr int Es = 256;   // embed
constexpr int NH = 8;     // heads
constexpr int DH = 32;    // head dim
constexpr int Mrows = Bb * Ns;        // 8192
constexpr int NX = Mrows * Es;        // 2097152
constexpr int NQ = 3 * Es * Es;       // 196608
constexpr int NP = Es * Es;           // 65536

typedef __bf16 bf16x8 __attribute__((ext_vector_type(8)));
typedef float  f32x4  __attribute__((ext_vector_type(4)));
union U4B8 { uint4 u; bf16x8 b; unsigned short s[8]; };

__device__ __forceinline__ unsigned short f2bf(float f) {
    union { float f; unsigned u; } c; c.f = f;
    unsigned r = (c.u + 0x7FFFu + ((c.u >> 16) & 1u)) >> 16;
    return (unsigned short)r;
}
__device__ __forceinline__ float bf2f(unsigned short h) {
    union { unsigned u; float f; } c; c.u = ((unsigned)h) << 16;
    return c.f;
}

#define GLD 72     // gemm LDS row stride (bf16)
#define PSTW 228   // fused-attn per-wave P row stride (bf16): 224 cols + 4 pad
#define AOST 264   // fused ao row stride (bf16): 256 cols + 8 pad

// ---------------------------------------------------------------------------
// Ledger: persistence -237us (grid barriers 60-110us each), occupancy +-0,
// no-LDS GEMM -21us (16-row scatter per load). R4 structure = 100.4us =
// harness poison-fill (~41us, timed) + 4 dispatches + 3 gaps + ~15us compute.
// This round: fuse attn+proj (zero redundant compute: one block = all 8 heads
// of one (b, 32-token tile) -> owns full 32x256 ao row block -> proj in-LDS).
// Removes 1 dispatch + 1 gap + 4MB aob round-trip. GEMM kernels = R4-verified.
// ---------------------------------------------------------------------------

// Kernel 0: cast x, qkv_w, proj_w fp32 -> bf16 once. 8 elems/thread.
__global__ __launch_bounds__(256, 8)
void cast_all(const float* __restrict__ x, const float* __restrict__ wq,
              const float* __restrict__ wp, unsigned short* __restrict__ xb,
              unsigned short* __restrict__ wqb, unsigned short* __restrict__ wpb)
{
    int i = (blockIdx.x * 256 + threadIdx.x) * 8;
    const float* src; unsigned short* dst;
    if (i < NX)            { src = x  + i;             dst = xb  + i; }
    else if (i < NX + NQ)  { src = wq + (i - NX);      dst = wqb + (i - NX); }
    else                   { src = wp + (i - NX - NQ); dst = wpb + (i - NX - NQ); }
    float4 f0 = *(const float4*)src;
    float4 f1 = *(const float4*)(src + 4);
    U4B8 u;
    u.s[0] = f2bf(f0.x); u.s[1] = f2bf(f0.y); u.s[2] = f2bf(f0.z); u.s[3] = f2bf(f0.w);
    u.s[4] = f2bf(f1.x); u.s[5] = f2bf(f1.y); u.s[6] = f2bf(f1.z); u.s[7] = f2bf(f1.w);
    *(uint4*)dst = u.u;
}

// ---------------------------------------------------------------------------
// Kernel 1: QKV GEMM (R4-verified: 64x64 tile, BK=64, LDS-staged).
// ---------------------------------------------------------------------------
__global__ __launch_bounds__(256, 8)
void qkv_gemm(const unsigned short* __restrict__ A, const unsigned short* __restrict__ W,
              const float* __restrict__ qkv_b,
              unsigned short* __restrict__ qo, unsigned short* __restrict__ ko,
              unsigned short* __restrict__ vto)
{
    __shared__ unsigned short As[64 * GLD];
    __shared__ unsigned short Ws[64 * GLD];

    const int t = threadIdx.x;
    const int m0 = (blockIdx.x & 127) * 64;
    const int j0 = (blockIdx.x >> 7) * 64;

    const int srow = t >> 2;
    const int scol = (t & 3) * 16;

    const int lane = t & 63;
    const int wave = t >> 6;
    const int wm = (wave & 1) * 32;
    const int wn = (wave >> 1) * 32;
    const int fm = lane & 15;
    const int fq = lane >> 4;

    f32x4 acc[2][2];
    #pragma unroll
    for (int i = 0; i < 2; i++)
        #pragma unroll
        for (int j = 0; j < 2; j++)
            acc[i][j] = (f32x4){0.f, 0.f, 0.f, 0.f};

    const unsigned short* Arow = A + (size_t)(m0 + srow) * Es;
    const unsigned short* Wrow = W + (size_t)(j0 + srow) * Es;

    for (int k0 = 0; k0 < Es; k0 += 64) {
        uint4 a0 = *(const uint4*)(Arow + k0 + scol);
        uint4 a1 = *(const uint4*)(Arow + k0 + scol + 8);
        uint4 w0 = *(const uint4*)(Wrow + k0 + scol);
        uint4 w1 = *(const uint4*)(Wrow + k0 + scol + 8);
        __syncthreads();
        *(uint4*)&As[srow * GLD + scol]     = a0;
        *(uint4*)&As[srow * GLD + scol + 8] = a1;
        *(uint4*)&Ws[srow * GLD + scol]     = w0;
        *(uint4*)&Ws[srow * GLD + scol + 8] = w1;
        __syncthreads();
        #pragma unroll
        for (int ks = 0; ks < 64; ks += 32) {
            U4B8 af0, af1, bf0, bf1;
            af0.u = *(const uint4*)&As[(wm +      fm) * GLD + ks + fq * 8];
            af1.u = *(const uint4*)&As[(wm + 16 + fm) * GLD + ks + fq * 8];
            bf0.u = *(const uint4*)&Ws[(wn +      fm) * GLD + ks + fq * 8];
            bf1.u = *(const uint4*)&Ws[(wn + 16 + fm) * GLD + ks + fq * 8];
            acc[0][0] = __builtin_amdgcn_mfma_f32_16x16x32_bf16(af0.b, bf0.b, acc[0][0], 0, 0, 0);
            acc[0][1] = __builtin_amdgcn_mfma_f32_16x16x32_bf16(af0.b, bf1.b, acc[0][1], 0, 0, 0);
            acc[1][0] = __builtin_amdgcn_mfma_f32_16x16x32_bf16(af1.b, bf0.b, acc[1][0], 0, 0, 0);
            acc[1][1] = __builtin_amdgcn_mfma_f32_16x16x32_bf16(af1.b, bf1.b, acc[1][1], 0, 0, 0);
        }
    }

    // C/D: col = lane&15, row = quad*4 + reg
    #pragma unroll
    for (int mt = 0; mt < 2; mt++) {
        #pragma unroll
        for (int nt = 0; nt < 2; nt++) {
            #pragma unroll
            for (int r = 0; r < 4; r++) {
                int row = m0 + wm + mt * 16 + fq * 4 + r;
                int col = j0 + wn + nt * 16 + fm;
                float val = acc[mt][nt][r] + qkv_b[col];
                int part = col >> 8;           // 0:q 1:k 2:v
                int head = (col >> 5) & 7;
                int d = col & 31;
                int b = row >> 10;
                int n = row & 1023;
                int bh = b * NH + head;
                if (part == 0)
                    qo[((size_t)bh * Ns + n) * DH + d] = f2bf(val * 0.0625f);
                else if (part == 1)
                    ko[((size_t)bh * Ns + n) * DH + d] = f2bf(val);
                else
                    vto[((size_t)bh * DH + d) * Ns + n] = f2bf(val);
            }
        }
    }
}

// ---------------------------------------------------------------------------
// Kernel 2: fused attention + projection.
// Grid 256 = (b, hq-tile). 512 threads = 8 waves: wave = (head-half, q-half).
// Round r2 in {0,1}: head = (w>>1) + 4*r2. Each wave does ALL 14 K-tiles
// (old sel-split merged) -> row sums are wave-local (no psum LDS/broadcast);
// inv[r] lives in the lanes owning PV row r. P is per-wave LDS [16][PSTW].
// PV output kept packed in 8 VGPRs across rounds; after both rounds the P
// region is dead and ao[32][AOST] aliases it. proj: A from LDS ao, W direct
// from L2-resident pwb (16 unrolled uint4 loads/wave), out += proj_b.
// ---------------------------------------------------------------------------
__global__ __launch_bounds__(512, 2)
void attn_proj(const unsigned short* __restrict__ qb, const unsigned short* __restrict__ kb,
               const unsigned short* __restrict__ vtb, const unsigned short* __restrict__ pw,
               const float* __restrict__ proj_b, float* __restrict__ out)
{
    __shared__ __align__(16) unsigned short SM[8 * 16 * PSTW];  // 58368 B
    // ao[32][AOST] (16896 B) aliases SM after P is dead.

    const int t    = threadIdx.x;
    const int w    = t >> 6;
    const int lane = t & 63;
    const int fm   = lane & 15;
    const int fq   = lane >> 4;

    const int blk = blockIdx.x;
    const int b   = blk & 7;       // XCD affinity: batch pinned
    const int hq  = blk >> 3;      // 0..31 query 32-tile

    int n0c = (hq - 3) * 32;
    n0c = n0c < 0 ? 0 : (n0c > Ns - 224 ? Ns - 224 : n0c);

    const int qbase = (w & 1) * 16;
    unsigned short* Pw = SM + w * 16 * PSTW;

    unsigned opack[2][2][2];   // [round][d2][word] : 4 bf16 per (round,d2)

    #pragma unroll
    for (int r2 = 0; r2 < 2; r2++) {
        const int h  = (w >> 1) + 4 * r2;
        const int bh = b * NH + h;

        // V^T fragment prefetch (B-operand: n=dim, k=key), both 16-dim tiles
        U4B8 vpre[2][7];
        #pragma unroll
        for (int d2 = 0; d2 < 2; d2++) {
            const unsigned short* vrow = vtb + ((size_t)bh * DH + d2 * 16 + fm) * Ns;
            #pragma unroll
            for (int i = 0; i < 7; i++)
                vpre[d2][i].u = *(const uint4*)(vrow + n0c + i * 32 + fq * 8);
        }

        // Q fragment
        U4B8 qa;
        qa.u = *(const uint4*)(qb + ((size_t)bh * Ns + hq * 32 + qbase + fm) * DH + fq * 8);

        // S = Q.K^T over all 14 key 16-tiles (key = kt*16+fm, query = qbase+fq*4+r)
        f32x4 sv[14];
        #pragma unroll
        for (int kt = 0; kt < 14; kt++) {
            U4B8 kf;
            kf.u = *(const uint4*)(kb + ((size_t)bh * Ns + n0c + kt * 16 + fm) * DH + fq * 8);
            sv[kt] = __builtin_amdgcn_mfma_f32_16x16x32_bf16(qa.b, kf.b, (f32x4){0.f,0.f,0.f,0.f}, 0, 0, 0);
        }

        __syncthreads();   // round1: prior round's P reads complete before overwrite

        // mask + exp (no max shift; |s|<~0.3) + P write + wave-local row sums
        float sm4[4] = {0.f, 0.f, 0.f, 0.f};
        #pragma unroll
        for (int kt = 0; kt < 14; kt++) {
            int g = n0c + kt * 16 + fm;
            int gh = g >> 5, gw = g & 31;
            int dhh = gh - hq;
            bool okh = (dhh >= -3) && (dhh <= 3);
            #pragma unroll
            for (int r = 0; r < 4; r++) {
                int qc = qbase + fq * 4 + r;
                int dww = gw - qc;
                bool ok = okh && (dww >= -5) && (dww <= 5);
                float p = ok ? __expf(sv[kt][r]) : 0.f;
                unsigned short pu = f2bf(p);
                Pw[(fq * 4 + r) * PSTW + kt * 16 + fm] = pu;
                sm4[r] += bf2f(pu);
            }
        }
        #pragma unroll
        for (int r = 0; r < 4; r++)
            #pragma unroll
            for (int m = 1; m < 16; m <<= 1)
                sm4[r] += __shfl_xor(sm4[r], m);
        float inv[4];
        #pragma unroll
        for (int r = 0; r < 4; r++)
            inv[r] = 1.f / sm4[r];

        __syncthreads();   // P committed to LDS (cross-lane read next)

        // O = P.V; rows of acc = fq*4+r == rows of sm4 -> scale in-lane
        #pragma unroll
        for (int d2 = 0; d2 < 2; d2++) {
            f32x4 acc = (f32x4){0.f, 0.f, 0.f, 0.f};
            #pragma unroll
            for (int i = 0; i < 7; i++) {
                U4B8 pa;
                pa.u = *(const uint4*)&Pw[fm * PSTW + i * 32 + fq * 8];
                acc = __builtin_amdgcn_mfma_f32_16x16x32_bf16(pa.b, vpre[d2][i].b, acc, 0, 0, 0);
            }
            unsigned p0 = (unsigned)f2bf(acc[0] * inv[0]) | ((unsigned)f2bf(acc[1] * inv[1]) << 16);
            unsigned p1 = (unsigned)f2bf(acc[2] * inv[2]) | ((unsigned)f2bf(acc[3] * inv[3]) << 16);
            opack[r2][d2][0] = p0;
            opack[r2][d2][1] = p1;
        }
    }

    __syncthreads();   // all PV reads done -> P region dead, alias as ao

    unsigned short* ao = SM;   // [32][AOST]
    #pragma unroll
    for (int r2 = 0; r2 < 2; r2++) {
        int h = (w >> 1) + 4 * r2;
        #pragma unroll
        for (int d2 = 0; d2 < 2; d2++) {
            #pragma unroll
            for (int r = 0; r < 4; r++) {
                unsigned word = opack[r2][d2][r >> 1];
                unsigned short v = (unsigned short)((r & 1) ? (word >> 16) : (word & 0xFFFFu));
                ao[(qbase + fq * 4 + r) * AOST + h * 32 + d2 * 16 + fm] = v;
            }
        }
    }

    __syncthreads();   // ao complete (proj reads all columns cross-wave)

    // proj: out[32 x 256] = ao @ pw^T + proj_b. Wave w owns cols w*32..w*32+31.
    const unsigned short* Wr0 = pw + (size_t)(w * 32 + fm) * Es + fq * 8;
    const unsigned short* Wr1 = Wr0 + 16 * Es;

    f32x4 pacc[2][2];
    #pragma unroll
    for (int i = 0; i < 2; i++)
        #pragma unroll
        for (int j = 0; j < 2; j++)
            pacc[i][j] = (f32x4){0.f, 0.f, 0.f, 0.f};

    #pragma unroll
    for (int ks = 0; ks < Es; ks += 32) {
        U4B8 a0, a1, w0, w1;
        a0.u = *(const uint4*)&ao[(fm)      * AOST + ks + fq * 8];
        a1.u = *(const uint4*)&ao[(16 + fm) * AOST + ks + fq * 8];
        w0.u = *(const uint4*)(Wr0 + ks);
        w1.u = *(const uint4*)(Wr1 + ks);
        pacc[0][0] = __builtin_amdgcn_mfma_f32_16x16x32_bf16(a0.b, w0.b, pacc[0][0], 0, 0, 0);
        pacc[0][1] = __builtin_amdgcn_mfma_f32_16x16x32_bf16(a0.b, w1.b, pacc[0][1], 0, 0, 0);
        pacc[1][0] = __builtin_amdgcn_mfma_f32_16x16x32_bf16(a1.b, w0.b, pacc[1][0], 0, 0, 0);
        pacc[1][1] = __builtin_amdgcn_mfma_f32_16x16x32_bf16(a1.b, w1.b, pacc[1][1], 0, 0, 0);
    }

    #pragma unroll
    for (int mt = 0; mt < 2; mt++) {
        #pragma unroll
        for (int nt = 0; nt < 2; nt++) {
            #pragma unroll
            for (int r = 0; r < 4; r++) {
                int row = hq * 32 + mt * 16 + fq * 4 + r;
                int col = w * 32 + nt * 16 + fm;
                out[((size_t)b * Ns + row) * Es + col] = pacc[mt][nt][r] + proj_b[col];
            }
        }
    }
}

extern "C" void kernel_launch(void* const* d_in, const int* in_sizes, int n_in,
                              void* d_out, int out_size, void* d_ws, size_t ws_size,
                              hipStream_t stream) {
    const float* x      = (const float*)d_in[0];  // [B,N,E]
    const float* qkv_w  = (const float*)d_in[1];  // [3E,E]
    const float* qkv_b  = (const float*)d_in[2];  // [3E]
    const float* proj_w = (const float*)d_in[3];  // [E,E]
    const float* proj_b = (const float*)d_in[4];  // [E]
    float* out = (float*)d_out;                   // [B,N,E]

    unsigned short* xb  = (unsigned short*)d_ws;  // NX bf16
    unsigned short* wqb = xb + NX;                // NQ bf16
    unsigned short* pwb = wqb + NQ;               // NP bf16
    unsigned short* qb  = pwb + NP;               // NX bf16 (q, scaled)
    unsigned short* kb  = qb + NX;                // NX bf16
    unsigned short* vtb = kb + NX;                // NX bf16 (transposed)

    cast_all<<<dim3((NX + NQ + NP) / 8 / 256), dim3(256), 0, stream>>>(
        x, qkv_w, proj_w, xb, wqb, pwb);

    qkv_gemm<<<dim3(1536), dim3(256), 0, stream>>>(xb, wqb, qkv_b, qb, kb, vtb);

    attn_proj<<<dim3(256), dim3(512), 0, stream>>>(qb, kb, vtb, pwb, proj_b, out);
}